// Round 5
// baseline (939.504 us; speedup 1.0000x reference)
//
#include <hip/hip_runtime.h>
#include <stdint.h>

// AUGRU (DIEN): B=1024, T=200, D=128, U=128.
// Phase 1 (parallel): xu/xr = f16(X@Wu_top/Wr_top) -> ws ; xc = f32(X@Wc_top) -> d_out
// Phase 2 (serial over T): h-part matmuls from LDS-resident f16 W_bot via v_dot2_f32_f16.
// R4 fix: ws usage is now ws_size-adaptive (T-chunked). Round-4 failure signature
// (call 1 correct, all later calls stably wrong) indicts OOB writes past d_ws
// corrupting the harness's pristine input copies; we previously assumed 105 MB of ws.
// h-state persists across chunks through d_out (out[b, t0-1, :] == running h).

#define NB 1024
#define NT 200
#define ND 128

typedef _Float16 h2_t __attribute__((ext_vector_type(2)));

__device__ __forceinline__ uint32_t packh2(float a, float b) {
  h2_t h; h.x = (_Float16)a; h.y = (_Float16)b;
  return __builtin_bit_cast(uint32_t, h);
}
__device__ __forceinline__ float2 h2f(uint32_t u) {
  h2_t h = __builtin_bit_cast(h2_t, u);
  return make_float2((float)h.x, (float)h.y);
}

#if __has_builtin(__builtin_amdgcn_fdot2)
__device__ __forceinline__ float DOT2(uint32_t a, uint32_t b, float c) {
  return __builtin_amdgcn_fdot2(__builtin_bit_cast(h2_t, a), __builtin_bit_cast(h2_t, b), c, false);
}
#else
__device__ __forceinline__ float DOT2(uint32_t a, uint32_t b, float c) {
  h2_t ha = __builtin_bit_cast(h2_t, a), hb = __builtin_bit_cast(h2_t, b);
  return fmaf((float)ha.y, (float)hb.y, fmaf((float)ha.x, (float)hb.x, c));
}
#endif

#if __has_builtin(__builtin_amdgcn_exp2f)
#define EXP2F(x) __builtin_amdgcn_exp2f(x)
#else
#define EXP2F(x) __expf((x) * 0.6931471805599453f)
#endif
#if __has_builtin(__builtin_amdgcn_rcpf)
#define RCPF(x) __builtin_amdgcn_rcpf(x)
#else
#define RCPF(x) (1.0f / (x))
#endif

__device__ __forceinline__ float sigmoidf_(float x) {
  return RCPF(1.0f + EXP2F(-1.44269504088896f * x));
}
__device__ __forceinline__ float tanhf_(float x) {
  x = fminf(10.0f, fmaxf(-10.0f, x));
  float e = EXP2F(2.88539008177793f * x);
  return (e - 1.0f) * RCPF(e + 1.0f);
}

// ---------------- Phase 1: x-projections for chunk t in [t0, t0+Tc) ----------------
// Grid-stride over 32-row tiles of the chunk-flat row space cr = b*Tc + (t-t0).
// Each block stages W_top (f16-packed) once. Wave w owns tile-rows w*8..w*8+7,
// lane j2 owns units 2j2, 2j2+1.
__global__ __launch_bounds__(256) void augru_p1(
    const float* __restrict__ x,
    const float* __restrict__ Wu, const float* __restrict__ Wr, const float* __restrict__ Wc,
    uint32_t* __restrict__ xu, uint32_t* __restrict__ xr, float* __restrict__ xc,
    int t0, int Tc, int total_tiles) {
  __shared__ __align__(16) uint32_t W2[3 * 64 * 128];  // [mat][d2][unit] half2 along K
  __shared__ __align__(16) uint32_t x2t[64 * 33];      // [d2][row] half2, pad 33
  const int tid = threadIdx.x;
  const float* Ws[3] = {Wu, Wr, Wc};
  for (int m = 0; m < 3; ++m)
    for (int idx = tid; idx < 8192; idx += 256) {
      int d2 = idx >> 7, j = idx & 127;
      float a = Ws[m][(2 * d2) * ND + j];
      float b = Ws[m][(2 * d2 + 1) * ND + j];
      W2[(m * 64 + d2) * 128 + j] = packh2(a, b);
    }
  const int w = tid >> 6, j2 = tid & 63;
  for (int gt = blockIdx.x; gt < total_tiles; gt += gridDim.x) {
    __syncthreads();  // protect x2t reuse (and W2 staging on first iter)
    for (int idx = tid; idx < 2048; idx += 256) {
      int rr = idx >> 6, d2 = idx & 63;  // consecutive d2 per lane -> coalesced global
      int cr = gt * 32 + rr;
      int b = cr / Tc, tt = cr - b * Tc;
      size_t mrow = (size_t)b * NT + t0 + tt;
      float2 v = *(const float2*)&x[mrow * ND + 2 * d2];
      x2t[d2 * 33 + rr] = packh2(v.x, v.y);
    }
    __syncthreads();
    float acc[8][6] = {};  // [row][{u0,u1,r0,r1,c0,c1}]
#pragma unroll 4
    for (int d2 = 0; d2 < 64; ++d2) {
      uint2 wu = *(const uint2*)&W2[(0 * 64 + d2) * 128 + 2 * j2];
      uint2 wr = *(const uint2*)&W2[(1 * 64 + d2) * 128 + 2 * j2];
      uint2 wc = *(const uint2*)&W2[(2 * 64 + d2) * 128 + 2 * j2];
#pragma unroll
      for (int rr = 0; rr < 8; ++rr) {
        uint32_t xv = x2t[d2 * 33 + w * 8 + rr];  // broadcast (same addr per wave)
        acc[rr][0] = DOT2(xv, wu.x, acc[rr][0]);
        acc[rr][1] = DOT2(xv, wu.y, acc[rr][1]);
        acc[rr][2] = DOT2(xv, wr.x, acc[rr][2]);
        acc[rr][3] = DOT2(xv, wr.y, acc[rr][3]);
        acc[rr][4] = DOT2(xv, wc.x, acc[rr][4]);
        acc[rr][5] = DOT2(xv, wc.y, acc[rr][5]);
      }
    }
#pragma unroll
    for (int rr = 0; rr < 8; ++rr) {
      const int cr = gt * 32 + w * 8 + rr;
      const int b = cr / Tc, tt = cr - b * Tc;
      const size_t mrow = (size_t)b * NT + t0 + tt;
      xu[(size_t)cr * 64 + j2] = packh2(acc[rr][0], acc[rr][1]);
      xr[(size_t)cr * 64 + j2] = packh2(acc[rr][2], acc[rr][3]);
      *(float2*)&xc[mrow * ND + 2 * j2] = make_float2(acc[rr][4], acc[rr][5]);
    }
  }
}

// ---------------- Phase 2: recurrence for t in [t0, t0+Tc) ----------------
// 256 blocks x 4 batch-rows; 256 threads = 4 waves. Matmul phases: wave kq owns a
// K-quarter (weights read once per block per step); reduce via LDS. Gate phases:
// wave index = row, u/h in registers. h / r*h transposed in LDS as half2.
// h-resume for t0>0: read out[row, t0-1, :] (== running h emitted by prev chunk).
__global__ __launch_bounds__(256) void augru_p2(
    const uint32_t* __restrict__ xu, const uint32_t* __restrict__ xr,
    const float* xc_in, const float* __restrict__ att,
    const int* __restrict__ slen,
    const float* __restrict__ Wu, const float* __restrict__ Wr, const float* __restrict__ Wc,
    float* out, int t0, int Tc) {
  __shared__ __align__(16) uint32_t W2[3 * 64 * 128];  // W_bot f16-packed [mat][d2][unit]
  __shared__ __align__(16) uint32_t h2t[512];          // [d2][row(pad8)] half2 of h
  __shared__ __align__(16) uint32_t rh2t[512];         // [d2][row(pad8)] half2 of r*h
  __shared__ __align__(16) float red[4096];            // K-split reduction buffer
  const int tid = threadIdx.x;
  const int kq = tid >> 6;  // wave: K-quarter in matmul phases, ROW in gate phases
  const int j2 = tid & 63;  // unit pair 2j2, 2j2+1
  const float* Ws[3] = {Wu, Wr, Wc};
  for (int m = 0; m < 3; ++m)
    for (int idx = tid; idx < 8192; idx += 256) {
      int d2 = idx >> 7, j = idx & 127;
      float a = Ws[m][(128 + 2 * d2) * ND + j];
      float b = Ws[m][(129 + 2 * d2) * ND + j];
      W2[(m * 64 + d2) * 128 + j] = packh2(a, b);
    }
  const int row = blockIdx.x * 4 + kq;
  const int sl = slen[row];
  float h0 = 0.f, h1 = 0.f;
  if (t0 > 0) {
    float2 hp = *(const float2*)&out[((size_t)row * NT + t0 - 1) * ND + 2 * j2];
    h0 = hp.x; h1 = hp.y;
  }
  h2t[j2 * 8 + kq] = packh2(h0, h1);  // each thread owns (row=kq, pair=j2): full coverage
  __syncthreads();
  for (int t = t0; t < t0 + Tc; ++t) {
    const size_t rt = (size_t)row * NT + t;
    const size_t cr = (size_t)row * Tc + (t - t0);
    // prefetch globals for this step (consumed after the matmul phases)
    const uint32_t xuv = xu[cr * 64 + j2];
    const uint32_t xrv = xr[cr * 64 + j2];
    const float2 xcv = *(const float2*)&xc_in[rt * ND + 2 * j2];
    const float av = att[rt];
    // ---- Phase A: partial dots for u, r over this wave's K-quarter ----
    float aU[4][2] = {};
    float aR[4][2] = {};
#pragma unroll
    for (int dd = 0; dd < 16; ++dd) {
      const int d2 = kq * 16 + dd;
      uint4 hv = *(const uint4*)&h2t[d2 * 8];  // broadcast: rows 0..3
      uint2 wu = *(const uint2*)&W2[(0 * 64 + d2) * 128 + 2 * j2];
      uint2 wr = *(const uint2*)&W2[(1 * 64 + d2) * 128 + 2 * j2];
      uint32_t hvv[4] = {hv.x, hv.y, hv.z, hv.w};
#pragma unroll
      for (int rr = 0; rr < 4; ++rr) {
        aU[rr][0] = DOT2(hvv[rr], wu.x, aU[rr][0]);
        aU[rr][1] = DOT2(hvv[rr], wu.y, aU[rr][1]);
        aR[rr][0] = DOT2(hvv[rr], wr.x, aR[rr][0]);
        aR[rr][1] = DOT2(hvv[rr], wr.y, aR[rr][1]);
      }
    }
#pragma unroll
    for (int rr = 0; rr < 4; ++rr)
      *(float4*)&red[((kq * 4 + rr) * 64 + j2) * 4] =
          make_float4(aU[rr][0], aU[rr][1], aR[rr][0], aR[rr][1]);
    __syncthreads();
    // ---- Phase B: finish u, r; write r*h (this thread = row kq, units 2j2..) ----
    float su0 = 0, su1 = 0, sr0 = 0, sr1 = 0;
#pragma unroll
    for (int k = 0; k < 4; ++k) {
      float4 v = *(const float4*)&red[((k * 4 + kq) * 64 + j2) * 4];
      su0 += v.x; su1 += v.y; sr0 += v.z; sr1 += v.w;
    }
    const float2 xuf = h2f(xuv), xrf = h2f(xrv);
    const float u0 = sigmoidf_(xuf.x + su0);
    const float u1 = sigmoidf_(xuf.y + su1);
    const float r0 = sigmoidf_(xrf.x + sr0);
    const float r1 = sigmoidf_(xrf.y + sr1);
    rh2t[j2 * 8 + kq] = packh2(r0 * h0, r1 * h1);
    __syncthreads();
    // ---- Phase C: partial dots for h_tilde ----
    float aC[4][2] = {};
#pragma unroll
    for (int dd = 0; dd < 16; ++dd) {
      const int d2 = kq * 16 + dd;
      uint4 rv = *(const uint4*)&rh2t[d2 * 8];
      uint2 wc = *(const uint2*)&W2[(2 * 64 + d2) * 128 + 2 * j2];
      uint32_t rvv[4] = {rv.x, rv.y, rv.z, rv.w};
#pragma unroll
      for (int rr = 0; rr < 4; ++rr) {
        aC[rr][0] = DOT2(rvv[rr], wc.x, aC[rr][0]);
        aC[rr][1] = DOT2(rvv[rr], wc.y, aC[rr][1]);
      }
    }
#pragma unroll
    for (int rr = 0; rr < 4; ++rr)
      *(float2*)&red[((kq * 4 + rr) * 64 + j2) * 2] = make_float2(aC[rr][0], aC[rr][1]);
    __syncthreads();
    // ---- Phase D: finish h_tilde, update h, emit ----
    float sc0 = 0, sc1 = 0;
#pragma unroll
    for (int k = 0; k < 4; ++k) {
      float2 v = *(const float2*)&red[((k * 4 + kq) * 64 + j2) * 2];
      sc0 += v.x; sc1 += v.y;
    }
    const float ht0 = tanhf_(xcv.x + sc0);
    const float ht1 = tanhf_(xcv.y + sc1);
    const float ut0 = u0 * av, ut1 = u1 * av;
    const float hn0 = h0 + ut0 * (ht0 - h0);
    const float hn1 = h1 + ut1 * (ht1 - h1);
    if (t < sl) { h0 = hn0; h1 = hn1; }  // uniform per wave (wave = row)
    *(float2*)&out[rt * ND + 2 * j2] = make_float2(h0, h1);
    h2t[j2 * 8 + kq] = packh2(h0, h1);
    __syncthreads();
  }
}

extern "C" void kernel_launch(void* const* d_in, const int* in_sizes, int n_in,
                              void* d_out, int out_size, void* d_ws, size_t ws_size,
                              hipStream_t stream) {
  const float* seq_emb = (const float*)d_in[0];
  const int* slen = (const int*)d_in[1];
  const float* att = (const float*)d_in[2];
  const float* Wu = (const float*)d_in[3];
  const float* Wr = (const float*)d_in[4];
  const float* Wc = (const float*)d_in[5];
  float* out = (float*)d_out;

  // Chunk size: largest divisor of NT whose xu+xr footprint (NB*Tc*512 B) fits ws_size.
  // Deterministic per session (ws_size is constant) -> same work on every call.
  const int tcs[] = {200, 100, 50, 40, 25, 20, 10, 8, 5, 4, 2};
  int Tc = 1;
  for (int i = 0; i < 11; ++i)
    if ((size_t)NB * tcs[i] * 512 <= ws_size) { Tc = tcs[i]; break; }

  uint32_t* xu = (uint32_t*)d_ws;             // [NB*Tc*64] half2
  uint32_t* xr = xu + (size_t)NB * Tc * 64;   // [NB*Tc*64] half2
  const int nch = NT / Tc;                    // exact: all candidates divide 200
  const int total_tiles = 32 * Tc;            // (NB*Tc)/32 tiles of 32 chunk-rows
  for (int k = 0; k < nch; ++k) {
    const int t0 = k * Tc;
    // xc (f32) for the chunk is staged in d_out and overwritten in-place by p2
    // (read-before-write per (b,t) by the same thread).
    augru_p1<<<256, 256, 0, stream>>>(seq_emb, Wu, Wr, Wc, xu, xr, out, t0, Tc, total_tiles);
    augru_p2<<<256, 256, 0, stream>>>(xu, xr, out, att, slen, Wu, Wr, Wc, out, t0, Tc);
  }
}

// Round 6
// 756.840 us; speedup vs baseline: 1.2414x; 1.2414x over previous
//
#include <hip/hip_runtime.h>
#include <stdint.h>

// AUGRU (DIEN): B=1024, T=200, D=128, U=128.
// R5: p1 split into 3 per-matrix GEMM blocks (3 blocks/CU, was 1); p2 uses raw
// s_barrier with LDS-only drain (kills the 4x/step vmcnt(0) HBM-latency drain),
// register-prefetches next step's globals, and caches W_bot K-quarter in VGPRs.

#define NB 1024
#define NT 200
#define ND 128

typedef _Float16 h2_t __attribute__((ext_vector_type(2)));

__device__ __forceinline__ uint32_t packh2(float a, float b) {
  h2_t h; h.x = (_Float16)a; h.y = (_Float16)b;
  return __builtin_bit_cast(uint32_t, h);
}
__device__ __forceinline__ float2 h2f(uint32_t u) {
  h2_t h = __builtin_bit_cast(h2_t, u);
  return make_float2((float)h.x, (float)h.y);
}

#if __has_builtin(__builtin_amdgcn_fdot2)
__device__ __forceinline__ float DOT2(uint32_t a, uint32_t b, float c) {
  return __builtin_amdgcn_fdot2(__builtin_bit_cast(h2_t, a), __builtin_bit_cast(h2_t, b), c, false);
}
#else
__device__ __forceinline__ float DOT2(uint32_t a, uint32_t b, float c) {
  h2_t ha = __builtin_bit_cast(h2_t, a), hb = __builtin_bit_cast(h2_t, b);
  return fmaf((float)ha.y, (float)hb.y, fmaf((float)ha.x, (float)hb.x, c));
}
#endif

#if __has_builtin(__builtin_amdgcn_exp2f)
#define EXP2F(x) __builtin_amdgcn_exp2f(x)
#else
#define EXP2F(x) __expf((x) * 0.6931471805599453f)
#endif
#if __has_builtin(__builtin_amdgcn_rcpf)
#define RCPF(x) __builtin_amdgcn_rcpf(x)
#else
#define RCPF(x) (1.0f / (x))
#endif

__device__ __forceinline__ float sigmoidf_(float x) {
  return RCPF(1.0f + EXP2F(-1.44269504088896f * x));
}
__device__ __forceinline__ float tanhf_(float x) {
  x = fminf(10.0f, fmaxf(-10.0f, x));
  float e = EXP2F(2.88539008177793f * x);
  return (e - 1.0f) * RCPF(e + 1.0f);
}

// LDS-only barrier: drains ds ops (read+write -> covers RAW and WAR across waves)
// but leaves global loads/stores in flight (no vmcnt drain). m194-m199 idiom.
__device__ __forceinline__ void lds_barrier() {
  asm volatile("s_waitcnt lgkmcnt(0)" ::: "memory");
  __builtin_amdgcn_s_barrier();
}

// ---------------- Phase 1: x-projections, one output matrix per block ----------------
// grid 768 = 3 matrices x 256 groups. LDS = 32K (W) + 8.7K (x2t) -> 3 blocks/CU.
// Per tile: 32 chunk-rows; wave w owns rows w*8..w*8+7, lane j2 owns units 2j2,2j2+1.
__global__ __launch_bounds__(256) void augru_p1(
    const float* __restrict__ x,
    const float* __restrict__ Wu, const float* __restrict__ Wr, const float* __restrict__ Wc,
    uint32_t* __restrict__ xu, uint32_t* __restrict__ xr, float* __restrict__ xc,
    int t0, int Tc, int total_tiles) {
  __shared__ __align__(16) uint32_t W2[64 * 128];  // one matrix, [d2][unit] half2 along K
  __shared__ __align__(16) uint32_t x2t[64 * 34];  // [d2][row] half2, pad 34 (even -> b64 reads ok)
  const int tid = threadIdx.x;
  const int m = blockIdx.x % 3;    // 0:u 1:r 2:c
  const int grp = blockIdx.x / 3;  // 0..255
  const float* W = (m == 0) ? Wu : (m == 1) ? Wr : Wc;
  for (int idx = tid; idx < 8192; idx += 256) {
    int d2 = idx >> 7, j = idx & 127;
    W2[d2 * 128 + j] = packh2(W[(2 * d2) * ND + j], W[(2 * d2 + 1) * ND + j]);
  }
  const int w = tid >> 6, j2 = tid & 63;
  for (int gt = grp; gt < total_tiles; gt += 256) {
    __syncthreads();  // protect x2t reuse (and W2 staging on first iter)
    for (int idx = tid; idx < 2048; idx += 256) {
      int rr = idx >> 6, d2 = idx & 63;  // consecutive d2 per lane -> coalesced global
      int cr = gt * 32 + rr;
      int b = cr / Tc, tt = cr - b * Tc;
      float2 v = *(const float2*)&x[((size_t)b * NT + t0 + tt) * ND + 2 * d2];
      x2t[d2 * 34 + rr] = packh2(v.x, v.y);  // stride-34 writes: ~4-way, near-free
    }
    __syncthreads();
    float acc[8][2] = {};
#pragma unroll 4
    for (int d2 = 0; d2 < 64; ++d2) {
      uint2 wv = *(const uint2*)&W2[d2 * 128 + 2 * j2];
      uint2 xq[4];
#pragma unroll
      for (int k = 0; k < 4; ++k)
        xq[k] = *(const uint2*)&x2t[d2 * 34 + w * 8 + 2 * k];  // wave-broadcast b64
#pragma unroll
      for (int k = 0; k < 4; ++k) {
        acc[2 * k][0] = DOT2(xq[k].x, wv.x, acc[2 * k][0]);
        acc[2 * k][1] = DOT2(xq[k].x, wv.y, acc[2 * k][1]);
        acc[2 * k + 1][0] = DOT2(xq[k].y, wv.x, acc[2 * k + 1][0]);
        acc[2 * k + 1][1] = DOT2(xq[k].y, wv.y, acc[2 * k + 1][1]);
      }
    }
    if (m < 2) {
      uint32_t* dst = m ? xr : xu;
#pragma unroll
      for (int rr = 0; rr < 8; ++rr)
        dst[(size_t)(gt * 32 + w * 8 + rr) * 64 + j2] = packh2(acc[rr][0], acc[rr][1]);
    } else {
#pragma unroll
      for (int rr = 0; rr < 8; ++rr) {
        int cr = gt * 32 + w * 8 + rr;
        int b = cr / Tc, tt = cr - b * Tc;
        *(float2*)&xc[((size_t)b * NT + t0 + tt) * ND + 2 * j2] =
            make_float2(acc[rr][0], acc[rr][1]);
      }
    }
  }
}

// ---------------- Phase 2: recurrence ----------------
// 256 blocks x 4 batch-rows; 4 waves. Wave kq owns K-quarter (W_bot quarter cached
// in VGPRs, statically indexed); gate phases: wave index = row. LDS only for
// h2t/rh2t/red (20.5 KB). Raw lgkm-only barriers; t+1 globals register-prefetched.
__global__ __launch_bounds__(256, 1) void augru_p2(
    const uint32_t* __restrict__ xu, const uint32_t* __restrict__ xr,
    const float* xc_in, const float* __restrict__ att,
    const int* __restrict__ slen,
    const float* __restrict__ Wu, const float* __restrict__ Wr, const float* __restrict__ Wc,
    float* out, int t0, int Tc) {
  __shared__ __align__(16) uint32_t h2t[512];   // [d2][row(pad8)] half2 of h
  __shared__ __align__(16) uint32_t rh2t[512];  // [d2][row(pad8)] half2 of r*h
  __shared__ __align__(16) float red[4096];     // K-split reduction buffer
  const int tid = threadIdx.x;
  const int kq = tid >> 6;  // wave: K-quarter in matmul phases, ROW in gate phases
  const int j2 = tid & 63;  // unit pair 2j2, 2j2+1

  // Cache this wave's W_bot K-quarter in registers: d2 in [16kq,16kq+16), units 2j2,2j2+1.
  uint2 wuR[16], wrR[16], wcR[16];
#pragma unroll
  for (int dd = 0; dd < 16; ++dd) {
    const int k0 = 128 + 2 * (kq * 16 + dd);
    float2 a, b;
    a = *(const float2*)&Wu[(size_t)k0 * ND + 2 * j2];
    b = *(const float2*)&Wu[(size_t)(k0 + 1) * ND + 2 * j2];
    wuR[dd].x = packh2(a.x, b.x); wuR[dd].y = packh2(a.y, b.y);
    a = *(const float2*)&Wr[(size_t)k0 * ND + 2 * j2];
    b = *(const float2*)&Wr[(size_t)(k0 + 1) * ND + 2 * j2];
    wrR[dd].x = packh2(a.x, b.x); wrR[dd].y = packh2(a.y, b.y);
    a = *(const float2*)&Wc[(size_t)k0 * ND + 2 * j2];
    b = *(const float2*)&Wc[(size_t)(k0 + 1) * ND + 2 * j2];
    wcR[dd].x = packh2(a.x, b.x); wcR[dd].y = packh2(a.y, b.y);
  }

  const int row = blockIdx.x * 4 + kq;
  const int sl = slen[row];
  float h0 = 0.f, h1 = 0.f;
  if (t0 > 0) {  // resume running h from previous chunk's emitted output
    float2 hp = *(const float2*)&out[((size_t)row * NT + t0 - 1) * ND + 2 * j2];
    h0 = hp.x; h1 = hp.y;
  }
  h2t[j2 * 8 + kq] = packh2(h0, h1);
  lds_barrier();

  const int t1 = t0 + Tc;
  // current-step operands (prologue load)
  uint32_t xuv = xu[((size_t)row * Tc) * 64 + j2];
  uint32_t xrv = xr[((size_t)row * Tc) * 64 + j2];
  float2 xcv = *(const float2*)&xc_in[((size_t)row * NT + t0) * ND + 2 * j2];
  float av = att[(size_t)row * NT + t0];

  for (int t = t0; t < t1; ++t) {
    const size_t rt = (size_t)row * NT + t;
    // ---- prefetch t+1 (clamped; consumed next iteration -> HBM latency hidden) ----
    const int tn = (t + 1 < t1) ? t + 1 : t;
    const size_t rtn = (size_t)row * NT + tn;
    const size_t crn = (size_t)row * Tc + (tn - t0);
    const uint32_t xuv_n = xu[crn * 64 + j2];
    const uint32_t xrv_n = xr[crn * 64 + j2];
    const float2 xcv_n = *(const float2*)&xc_in[rtn * ND + 2 * j2];
    const float av_n = att[rtn];
    // ---- Phase A: partial dots for u, r over this wave's K-quarter ----
    float aU[4][2] = {};
    float aR[4][2] = {};
#pragma unroll
    for (int dd = 0; dd < 16; ++dd) {
      const int d2 = kq * 16 + dd;
      uint4 hv = *(const uint4*)&h2t[d2 * 8];  // wave-broadcast
      uint32_t hvv[4] = {hv.x, hv.y, hv.z, hv.w};
#pragma unroll
      for (int rr = 0; rr < 4; ++rr) {
        aU[rr][0] = DOT2(hvv[rr], wuR[dd].x, aU[rr][0]);
        aU[rr][1] = DOT2(hvv[rr], wuR[dd].y, aU[rr][1]);
        aR[rr][0] = DOT2(hvv[rr], wrR[dd].x, aR[rr][0]);
        aR[rr][1] = DOT2(hvv[rr], wrR[dd].y, aR[rr][1]);
      }
    }
#pragma unroll
    for (int rr = 0; rr < 4; ++rr)
      *(float4*)&red[((kq * 4 + rr) * 64 + j2) * 4] =
          make_float4(aU[rr][0], aU[rr][1], aR[rr][0], aR[rr][1]);
    lds_barrier();
    // ---- Phase B: finish u, r; write r*h (this thread = row kq, units 2j2..) ----
    float su0 = 0, su1 = 0, sr0 = 0, sr1 = 0;
#pragma unroll
    for (int k = 0; k < 4; ++k) {
      float4 v = *(const float4*)&red[((k * 4 + kq) * 64 + j2) * 4];
      su0 += v.x; su1 += v.y; sr0 += v.z; sr1 += v.w;
    }
    const float2 xuf = h2f(xuv), xrf = h2f(xrv);
    const float u0 = sigmoidf_(xuf.x + su0);
    const float u1 = sigmoidf_(xuf.y + su1);
    const float r0 = sigmoidf_(xrf.x + sr0);
    const float r1 = sigmoidf_(xrf.y + sr1);
    rh2t[j2 * 8 + kq] = packh2(r0 * h0, r1 * h1);
    lds_barrier();
    // ---- Phase C: partial dots for h_tilde ----
    float aC[4][2] = {};
#pragma unroll
    for (int dd = 0; dd < 16; ++dd) {
      const int d2 = kq * 16 + dd;
      uint4 rv = *(const uint4*)&rh2t[d2 * 8];
      uint32_t rvv[4] = {rv.x, rv.y, rv.z, rv.w};
#pragma unroll
      for (int rr = 0; rr < 4; ++rr) {
        aC[rr][0] = DOT2(rvv[rr], wcR[dd].x, aC[rr][0]);
        aC[rr][1] = DOT2(rvv[dd < 16 ? rr : rr], wcR[dd].y, aC[rr][1]);
      }
    }
#pragma unroll
    for (int rr = 0; rr < 4; ++rr)
      *(float2*)&red[((kq * 4 + rr) * 64 + j2) * 2] = make_float2(aC[rr][0], aC[rr][1]);
    lds_barrier();
    // ---- Phase D: finish h_tilde, update h, emit ----
    float sc0 = 0, sc1 = 0;
#pragma unroll
    for (int k = 0; k < 4; ++k) {
      float2 v = *(const float2*)&red[((k * 4 + kq) * 64 + j2) * 2];
      sc0 += v.x; sc1 += v.y;
    }
    const float ht0 = tanhf_(xcv.x + sc0);
    const float ht1 = tanhf_(xcv.y + sc1);
    const float ut0 = u0 * av, ut1 = u1 * av;
    const float hn0 = h0 + ut0 * (ht0 - h0);
    const float hn1 = h1 + ut1 * (ht1 - h1);
    if (t < sl) { h0 = hn0; h1 = hn1; }  // uniform per wave (wave = row)
    *(float2*)&out[rt * ND + 2 * j2] = make_float2(h0, h1);  // fire-and-forget
    h2t[j2 * 8 + kq] = packh2(h0, h1);
    lds_barrier();
    // rotate prefetched operands
    xuv = xuv_n; xrv = xrv_n; xcv = xcv_n; av = av_n;
  }
}

extern "C" void kernel_launch(void* const* d_in, const int* in_sizes, int n_in,
                              void* d_out, int out_size, void* d_ws, size_t ws_size,
                              hipStream_t stream) {
  const float* seq_emb = (const float*)d_in[0];
  const int* slen = (const int*)d_in[1];
  const float* att = (const float*)d_in[2];
  const float* Wu = (const float*)d_in[3];
  const float* Wr = (const float*)d_in[4];
  const float* Wc = (const float*)d_in[5];
  float* out = (float*)d_out;

  // Chunk size: largest divisor of NT whose xu+xr footprint (NB*Tc*512 B) fits ws_size.
  const int tcs[] = {200, 100, 50, 40, 25, 20, 10, 8, 5, 4, 2};
  int Tc = 1;
  for (int i = 0; i < 11; ++i)
    if ((size_t)NB * tcs[i] * 512 <= ws_size) { Tc = tcs[i]; break; }

  uint32_t* xu = (uint32_t*)d_ws;            // [NB*Tc*64] half2
  uint32_t* xr = xu + (size_t)NB * Tc * 64;  // [NB*Tc*64] half2
  const int nch = NT / Tc;
  const int total_tiles = 32 * Tc;  // (NB*Tc)/32 tiles of 32 chunk-rows
  for (int k = 0; k < nch; ++k) {
    const int t0 = k * Tc;
    // xc (f32) for the chunk is staged in d_out and overwritten in-place by p2.
    augru_p1<<<768, 256, 0, stream>>>(seq_emb, Wu, Wr, Wc, xu, xr, out, t0, Tc, total_tiles);
    augru_p2<<<256, 256, 0, stream>>>(xu, xr, out, att, slen, Wu, Wr, Wc, out, t0, Tc);
  }
}

// Round 7
// 584.035 us; speedup vs baseline: 1.6086x; 1.2959x over previous
//
#include <hip/hip_runtime.h>
#include <stdint.h>

// AUGRU (DIEN): B=1024, T=200, D=128, U=128.
// R6: both matmul phases moved to MFMA f16 (v_dot2 measured ~half-rate -> VALU
// roofline ~128us/kernel; matrix pipe is the only way below). p1: x@W_top GEMM,
// all 3 projections f16 -> proj[cr][384] in ws. p2: 256 blocks x 4 rows, per step
// 24 MFMA/wave, h in owner registers, 2 LDS-only barriers/step, W_bot in VGPRs.

#define NB 1024
#define NT 200
#define ND 128

typedef _Float16 f16;
typedef _Float16 f16x8 __attribute__((ext_vector_type(8)));
typedef float f32x4 __attribute__((ext_vector_type(4)));

__device__ __forceinline__ f32x4 MF(f16x8 a, f16x8 b, f32x4 c) {
  return __builtin_amdgcn_mfma_f32_16x16x32_f16(a, b, c, 0, 0, 0);
}

#if __has_builtin(__builtin_amdgcn_exp2f)
#define EXP2F(x) __builtin_amdgcn_exp2f(x)
#else
#define EXP2F(x) __expf((x) * 0.6931471805599453f)
#endif
#if __has_builtin(__builtin_amdgcn_rcpf)
#define RCPF(x) __builtin_amdgcn_rcpf(x)
#else
#define RCPF(x) (1.0f / (x))
#endif

__device__ __forceinline__ float sigmoidf_(float x) {
  return RCPF(1.0f + EXP2F(-1.44269504088896f * x));
}
__device__ __forceinline__ float tanhf_(float x) {
  x = fminf(10.0f, fmaxf(-10.0f, x));
  float e = EXP2F(2.88539008177793f * x);
  return (e - 1.0f) * RCPF(e + 1.0f);
}

// LDS-only barrier: drains ds ops but leaves global loads/stores in flight.
__device__ __forceinline__ void lds_barrier() {
  asm volatile("s_waitcnt lgkmcnt(0)" ::: "memory");
  __builtin_amdgcn_s_barrier();
}

// ---------------- Phase 1: proj[cr][0:384] = f16( x[row] @ [Wu|Wr|Wc]_top ) ----------
// MFMA GEMM, 16-row tiles. Wave w owns flat ntiles 6w..6w+5 (N=384 = 24 ntiles);
// B-frags (96 VGPR) loaded once; A staged f32->f16 in LDS per tile.
__global__ __launch_bounds__(256, 2) void augru_p1(
    const float* __restrict__ x, const float* __restrict__ Wu,
    const float* __restrict__ Wr, const float* __restrict__ Wc,
    f16* __restrict__ proj, int t0, int Tc, int ntiles) {
  __shared__ __align__(16) f16 xt[16][136];  // [row][k], pad 136 (~2-way banks)
  const int tid = threadIdx.x, w = tid >> 6, l = tid & 63;
  // B fragment layout: n = lane&15, k = kt*32 + (lane>>4)*8 + e (k-map cancels A vs B)
  f16x8 Bf[6][4];
#pragma unroll
  for (int i = 0; i < 6; ++i) {
    const int nt = 6 * w + i;
    const float* W = (nt < 8) ? Wu : (nt < 16) ? Wr : Wc;
    const int col = ((nt & 7) << 4) + (l & 15);
#pragma unroll
    for (int kt = 0; kt < 4; ++kt)
#pragma unroll
      for (int e = 0; e < 8; ++e)
        Bf[i][kt][e] = (f16)W[(size_t)(kt * 32 + ((l >> 4) << 3) + e) * ND + col];
  }
  const int srow = tid >> 4, sc = (tid & 15) << 3;
  for (int gt = blockIdx.x; gt < ntiles; gt += gridDim.x) {
    lds_barrier();  // protect xt reuse (no vmcnt drain: proj stores stay in flight)
    {
      const int cr = gt * 16 + srow;
      const int b = cr / Tc, tt = cr - b * Tc;
      const float* px = &x[((size_t)b * NT + t0 + tt) * ND + sc];
      const float4 v0 = *(const float4*)px, v1 = *(const float4*)(px + 4);
      f16x8 hv;
      hv[0] = (f16)v0.x; hv[1] = (f16)v0.y; hv[2] = (f16)v0.z; hv[3] = (f16)v0.w;
      hv[4] = (f16)v1.x; hv[5] = (f16)v1.y; hv[6] = (f16)v1.z; hv[7] = (f16)v1.w;
      *(f16x8*)&xt[srow][sc] = hv;  // ds_write_b128
    }
    lds_barrier();
    f16x8 Af[4];
#pragma unroll
    for (int kt = 0; kt < 4; ++kt)
      Af[kt] = *(const f16x8*)&xt[l & 15][kt * 32 + ((l >> 4) << 3)];
    f32x4 acc[6];
#pragma unroll
    for (int i = 0; i < 6; ++i) acc[i] = (f32x4){0.f, 0.f, 0.f, 0.f};
#pragma unroll
    for (int i = 0; i < 6; ++i)
#pragma unroll
      for (int kt = 0; kt < 4; ++kt) acc[i] = MF(Af[kt], Bf[i][kt], acc[i]);
    // C/D: col = lane&15 (-> ntile*16+col), row = (lane>>4)*4 + reg
#pragma unroll
    for (int i = 0; i < 6; ++i) {
      const int nt = 6 * w + i;
#pragma unroll
      for (int reg = 0; reg < 4; ++reg) {
        const int cr2 = gt * 16 + ((l >> 4) << 2) + reg;
        proj[(size_t)cr2 * 384 + (nt << 4) + (l & 15)] = (f16)acc[i][reg];
      }
    }
  }
}

// ---------------- Phase 2: recurrence, MFMA ----------------
// 256 blocks x 4 rows x 4 waves. Wave w owns output cols 32w..32w+31 (ntiles 2w,2w+1).
// Per step: 16 MFMA (u,r) + 8 MFMA (c). MFMA rows 4-15 are garbage (row-separable,
// ignored). Gate owners = lanes 0-15: elem (row=reg, col=32w+(l&15)+16i), h in regs.
__global__ __launch_bounds__(256, 1) void augru_p2(
    const f16* __restrict__ proj, const float* __restrict__ att,
    const int* __restrict__ slen, const float* __restrict__ Wu,
    const float* __restrict__ Wr, const float* __restrict__ Wc,
    float* __restrict__ out, int t0, int Tc) {
  __shared__ __align__(16) f16 h_lds[16][136];
  __shared__ __align__(16) f16 rh_lds[16][136];
  const int tid = threadIdx.x, w = tid >> 6, l = tid & 63;
  const int rowbase = blockIdx.x << 2;
  // B frags from W bottom half (rows 128..255): 96 VGPR
  f16x8 Bu[2][4], Br[2][4], Bc[2][4];
#pragma unroll
  for (int i = 0; i < 2; ++i) {
    const int col = ((2 * w + i) << 4) + (l & 15);
#pragma unroll
    for (int kt = 0; kt < 4; ++kt)
#pragma unroll
      for (int e = 0; e < 8; ++e) {
        const size_t k = 128 + kt * 32 + ((l >> 4) << 3) + e;
        Bu[i][kt][e] = (f16)Wu[k * ND + col];
        Br[i][kt][e] = (f16)Wr[k * ND + col];
        Bc[i][kt][e] = (f16)Wc[k * ND + col];
      }
  }
  {  // zero LDS once (rows 4-15 stay zero forever)
    f16* hp = &h_lds[0][0];
    f16* rp = &rh_lds[0][0];
    for (int idx = tid; idx < 16 * 136; idx += 256) { hp[idx] = (f16)0.f; rp[idx] = (f16)0.f; }
  }
  const bool owner = (l >> 4) == 0;
  const int c0 = (w << 5) + (l & 15);  // owned cols: c0, c0+16
  float h[4][2];
  int sl[4];
#pragma unroll
  for (int r = 0; r < 4; ++r) { sl[r] = slen[rowbase + r]; h[r][0] = 0.f; h[r][1] = 0.f; }
  if (t0 > 0 && owner) {
#pragma unroll
    for (int r = 0; r < 4; ++r)
#pragma unroll
      for (int i = 0; i < 2; ++i)
        h[r][i] = out[((size_t)(rowbase + r) * NT + t0 - 1) * ND + c0 + 16 * i];
  }
  if (owner) {
#pragma unroll
    for (int r = 0; r < 4; ++r)
#pragma unroll
      for (int i = 0; i < 2; ++i) h_lds[r][c0 + 16 * i] = (f16)h[r][i];
  }
  __syncthreads();

#define LOAD_STEP(T, XU, XR, XC, AT)                                      \
  if (owner) {                                                            \
    const int ttc = (T) - t0;                                             \
    _Pragma("unroll") for (int r = 0; r < 4; ++r) {                       \
      const size_t cr = (size_t)(rowbase + r) * Tc + ttc;                 \
      _Pragma("unroll") for (int i = 0; i < 2; ++i) {                     \
        XU[r][i] = (float)proj[cr * 384 + c0 + 16 * i];                   \
        XR[r][i] = (float)proj[cr * 384 + 128 + c0 + 16 * i];             \
        XC[r][i] = (float)proj[cr * 384 + 256 + c0 + 16 * i];             \
      }                                                                   \
      AT[r] = att[(size_t)(rowbase + r) * NT + (T)];                      \
    }                                                                     \
  }

  const int t1 = t0 + Tc;
  float xu_c[4][2], xr_c[4][2], xc_c[4][2], att_c[4];
  LOAD_STEP(t0, xu_c, xr_c, xc_c, att_c);
  for (int t = t0; t < t1; ++t) {
    // prefetch t+1 (vmcnt not drained by lds_barrier -> hidden under this step)
    float xu_n[4][2], xr_n[4][2], xc_n[4][2], att_n[4];
    const int tn = (t + 1 < t1) ? t + 1 : t;
    LOAD_STEP(tn, xu_n, xr_n, xc_n, att_n);
    // ---- u,r matmuls ----
    f16x8 Af[4];
#pragma unroll
    for (int kt = 0; kt < 4; ++kt)
      Af[kt] = *(const f16x8*)&h_lds[l & 15][kt * 32 + ((l >> 4) << 3)];
    f32x4 au[2], ar[2];
    au[0] = (f32x4){0.f, 0.f, 0.f, 0.f}; au[1] = au[0]; ar[0] = au[0]; ar[1] = au[0];
#pragma unroll
    for (int i = 0; i < 2; ++i)
#pragma unroll
      for (int kt = 0; kt < 4; ++kt) {
        au[i] = MF(Af[kt], Bu[i][kt], au[i]);
        ar[i] = MF(Af[kt], Br[i][kt], ar[i]);
      }
    // ---- gates: u, r; write r*h ----
    float uu[4][2];
    if (owner) {
#pragma unroll
      for (int r = 0; r < 4; ++r)
#pragma unroll
        for (int i = 0; i < 2; ++i) {
          const float u = sigmoidf_(xu_c[r][i] + au[i][r]);
          const float rg = sigmoidf_(xr_c[r][i] + ar[i][r]);
          uu[r][i] = u * att_c[r];
          rh_lds[r][c0 + 16 * i] = (f16)(rg * h[r][i]);
        }
    }
    lds_barrier();
    // ---- c matmul ----
    f16x8 Rf[4];
#pragma unroll
    for (int kt = 0; kt < 4; ++kt)
      Rf[kt] = *(const f16x8*)&rh_lds[l & 15][kt * 32 + ((l >> 4) << 3)];
    f32x4 ac[2];
    ac[0] = (f32x4){0.f, 0.f, 0.f, 0.f}; ac[1] = ac[0];
#pragma unroll
    for (int i = 0; i < 2; ++i)
#pragma unroll
      for (int kt = 0; kt < 4; ++kt) ac[i] = MF(Rf[kt], Bc[i][kt], ac[i]);
    // ---- h update, emit ----
    if (owner) {
#pragma unroll
      for (int r = 0; r < 4; ++r)
#pragma unroll
        for (int i = 0; i < 2; ++i) {
          const float htil = tanhf_(xc_c[r][i] + ac[i][r]);
          const float hn = h[r][i] + uu[r][i] * (htil - h[r][i]);
          if (t < sl[r]) h[r][i] = hn;  // freeze past seq_length
          out[((size_t)(rowbase + r) * NT + t) * ND + c0 + 16 * i] = h[r][i];
          h_lds[r][c0 + 16 * i] = (f16)h[r][i];
        }
    }
    lds_barrier();
#pragma unroll
    for (int r = 0; r < 4; ++r) {
      att_c[r] = att_n[r];
#pragma unroll
      for (int i = 0; i < 2; ++i) {
        xu_c[r][i] = xu_n[r][i]; xr_c[r][i] = xr_n[r][i]; xc_c[r][i] = xc_n[r][i];
      }
    }
  }
#undef LOAD_STEP
}

extern "C" void kernel_launch(void* const* d_in, const int* in_sizes, int n_in,
                              void* d_out, int out_size, void* d_ws, size_t ws_size,
                              hipStream_t stream) {
  const float* seq_emb = (const float*)d_in[0];
  const int* slen = (const int*)d_in[1];
  const float* att = (const float*)d_in[2];
  const float* Wu = (const float*)d_in[3];
  const float* Wr = (const float*)d_in[4];
  const float* Wc = (const float*)d_in[5];
  float* out = (float*)d_out;

  // Chunk: largest divisor of NT with proj footprint NB*Tc*384*2 B <= ws_size.
  // ws >= 105 MB (proven R5/R6) -> Tc >= 100.
  const int tcs[] = {200, 100, 50, 40, 25, 20, 10, 8, 5, 4, 2};
  int Tc = 1;
  for (int i = 0; i < 11; ++i)
    if ((size_t)NB * tcs[i] * 768 <= ws_size) { Tc = tcs[i]; break; }

  f16* proj = (f16*)d_ws;  // [NB*Tc][384] f16: cols 0-127 u, 128-255 r, 256-383 c
  const int nch = NT / Tc;
  const int ntiles = NB * Tc / 16;
  for (int k = 0; k < nch; ++k) {
    const int t0 = k * Tc;
    augru_p1<<<512, 256, 0, stream>>>(seq_emb, Wu, Wr, Wc, proj, t0, Tc, ntiles);
    augru_p2<<<256, 256, 0, stream>>>(proj, att, slen, Wu, Wr, Wc, out, t0, Tc);
  }
}